// Round 11
// baseline (234.989 us; speedup 1.0000x reference)
//
#include <hip/hip_runtime.h>
#include <hip/hip_bf16.h>

typedef __attribute__((ext_vector_type(8))) short short8;
typedef __attribute__((ext_vector_type(4))) float f32x4;
typedef __attribute__((ext_vector_type(16))) float f32x16;

static __device__ __forceinline__ unsigned short f2bf(float f) {
    unsigned int u = __builtin_bit_cast(unsigned int, f);
    u += 0x7fff + ((u >> 16) & 1);   // round-to-nearest-even
    return (unsigned short)(u >> 16);
}

static __device__ __forceinline__ float bf2f(unsigned short u) {
    return __builtin_bit_cast(float, (unsigned int)u << 16);
}

// truncating bf16 pack of two floats -> one u32 (lo=a, hi=b)
static __device__ __forceinline__ unsigned int pkbf(float a, float b) {
    return (__builtin_bit_cast(unsigned int, b) & 0xffff0000u) |
           (__builtin_bit_cast(unsigned int, a) >> 16);
}

// direct HBM -> LDS DMA, 16B/lane; LDS dest is wave-uniform base (HW adds lane*16)
static __device__ __forceinline__ void gl_lds16(const unsigned short* g, unsigned short* l) {
    __builtin_amdgcn_global_load_lds(
        (const __attribute__((address_space(1))) unsigned int*)g,
        (__attribute__((address_space(3))) unsigned int*)l, 16, 0, 0);
}

// ---------------- fp32 -> bf16 elementwise convert (vectorized 8/thread) ----
__global__ __launch_bounds__(256) void k_f32_to_bf16(
    const float* __restrict__ in, unsigned short* __restrict__ out, long n)
{
    long i = ((long)blockIdx.x * 256 + threadIdx.x) * 8;
    if (i >= n) return;
    const f32x4 a = *reinterpret_cast<const f32x4*>(in + i);
    const f32x4 b = *reinterpret_cast<const f32x4*>(in + i + 4);
    union { unsigned short u[8]; uint4 v; } o;
    o.u[0] = f2bf(a[0]); o.u[1] = f2bf(a[1]); o.u[2] = f2bf(a[2]); o.u[3] = f2bf(a[3]);
    o.u[4] = f2bf(b[0]); o.u[5] = f2bf(b[1]); o.u[6] = f2bf(b[2]); o.u[7] = f2bf(b[3]);
    *reinterpret_cast<uint4*>(out + i) = o.v;
}

// ---------------- w [K][N] f32 -> wt [N][K] bf16 (tiled transpose) ----------
__global__ __launch_bounds__(256) void k_transpose_w(
    const float* __restrict__ w, unsigned short* __restrict__ wt, int K, int N)
{
    __shared__ unsigned short tile[64][72];
    const int k0 = blockIdx.x * 64, n0 = blockIdx.y * 64;
    const int tid = threadIdx.x;
#pragma unroll
    for (int it = 0; it < 4; ++it) {
        int idx = it * 256 + tid;          // 1024 float4 chunks
        int kl = idx >> 4;
        int nl = (idx & 15) * 4;
        f32x4 v = *reinterpret_cast<const f32x4*>(w + (long)(k0 + kl) * N + n0 + nl);
        tile[kl][nl + 0] = f2bf(v[0]);
        tile[kl][nl + 1] = f2bf(v[1]);
        tile[kl][nl + 2] = f2bf(v[2]);
        tile[kl][nl + 3] = f2bf(v[3]);
    }
    __syncthreads();
#pragma unroll
    for (int it = 0; it < 2; ++it) {
        int idx = it * 256 + tid;          // 512 chunks of 8
        int nl = idx >> 3;
        int c  = (idx & 7) * 8;
        union { unsigned short u[8]; uint4 v; } o;
#pragma unroll
        for (int j = 0; j < 8; ++j) o.u[j] = tile[c + j][nl];
        *reinterpret_cast<uint4*>(wt + (long)(n0 + nl) * K + k0 + c) = o.v;
    }
}

// ---------------- GEMM: C[M][N] = A[M][K] * Bt[N][K]^T + bias --------------
// A, Bt bf16 K-major; out bf16 (OUTF32=0) or f32 (OUTF32=1).
template <int OUTF32>
__global__ __launch_bounds__(256) void k_gemm_bt(
    const unsigned short* __restrict__ A,
    const unsigned short* __restrict__ Bt,
    const float* __restrict__ bias,
    void* __restrict__ Cv, int M, int N, int K)
{
    __shared__ unsigned short As[128][72];
    __shared__ unsigned short Bs[128][72];
    const int tid = threadIdx.x;
    const int m0 = blockIdx.x * 128;
    const int n0 = blockIdx.y * 128;
    const int w = tid >> 6, lane = tid & 63;
    const int wr = (w >> 1) * 64, wc = (w & 1) * 64;
    const int l4 = lane >> 4, l15 = lane & 15;

    f32x4 acc[4][4] = {};
    const int nk = K / 64;
    for (int kt = 0; kt < nk; ++kt) {
        const int k0 = kt * 64;
        __syncthreads();
#pragma unroll
        for (int it = 0; it < 4; ++it) {
            int idx = it * 256 + tid;      // 1024 chunks of 8 bf16
            int r = idx >> 3, c = (idx & 7) * 8;
            *reinterpret_cast<uint4*>(&As[r][c]) =
                *reinterpret_cast<const uint4*>(A + (long)(m0 + r) * K + k0 + c);
            *reinterpret_cast<uint4*>(&Bs[r][c]) =
                *reinterpret_cast<const uint4*>(Bt + (long)(n0 + r) * K + k0 + c);
        }
        __syncthreads();
#pragma unroll
        for (int kk = 0; kk < 2; ++kk) {
            short8 af[4], bf[4];
#pragma unroll
            for (int m = 0; m < 4; ++m)
                af[m] = *reinterpret_cast<const short8*>(&As[wr + m * 16 + l15][kk * 32 + l4 * 8]);
#pragma unroll
            for (int n = 0; n < 4; ++n)
                bf[n] = *reinterpret_cast<const short8*>(&Bs[wc + n * 16 + l15][kk * 32 + l4 * 8]);
#pragma unroll
            for (int m = 0; m < 4; ++m)
#pragma unroll
                for (int n = 0; n < 4; ++n)
                    acc[m][n] = __builtin_amdgcn_mfma_f32_16x16x32_bf16(af[m], bf[n], acc[m][n], 0, 0, 0);
        }
    }
    // epilogue
#pragma unroll
    for (int n = 0; n < 4; ++n) {
        const int col = n0 + wc + n * 16 + l15;
        const float bv = bias[col];
#pragma unroll
        for (int m = 0; m < 4; ++m) {
            const int row = m0 + wr + m * 16 + l4 * 4;
#pragma unroll
            for (int i = 0; i < 4; ++i) {
                float v = acc[m][n][i] + bv;
                if (OUTF32)
                    reinterpret_cast<float*>(Cv)[(long)(row + i) * N + col] = v;
                else
                    reinterpret_cast<unsigned short*>(Cv)[(long)(row + i) * N + col] = f2bf(v);
            }
        }
    }
}

// ---------------- V transpose: qkv v-part -> vt[bh][d=64][T] ---------------
__global__ __launch_bounds__(256) void k_transpose_v(
    const unsigned short* __restrict__ qkv, unsigned short* __restrict__ vt, int T)
{
    __shared__ unsigned short tile[64][72];
    const int t0 = blockIdx.x * 64, bh = blockIdx.y;
    const int b = bh >> 4, h = bh & 15;
    const int tid = threadIdx.x;
#pragma unroll
    for (int it = 0; it < 2; ++it) {
        int idx = it * 256 + tid;
        int r = idx >> 3, c = (idx & 7) * 8;
        *reinterpret_cast<uint4*>(&tile[r][c]) =
            *reinterpret_cast<const uint4*>(qkv + (long)(b * T + t0 + r) * 3072 + 2048 + h * 64 + c);
    }
    __syncthreads();
#pragma unroll
    for (int it = 0; it < 2; ++it) {
        int idx = it * 256 + tid;
        int d = idx >> 3, c = (idx & 7) * 8;
        union { unsigned short u[8]; uint4 v; } o;
#pragma unroll
        for (int j = 0; j < 8; ++j) o.u[j] = tile[c + j][d];
        *reinterpret_cast<uint4*>(vt + ((long)bh * 64 + d) * T + t0 + c) = o.v;
    }
}

// ---------------- causal flash attention v7: 32x32 MFMA, in-register P -----
// Paired q-tiles (qa, qb=31-qa). Each wave owns 32 q-rows: lanes q31<16 ->
// tile-B rows [w*16..), q31>=16 -> tile-A rows. Swapped QK^T via
// mfma_f32_32x32x16_bf16 (S^T = K · Q^T): lane holds P^T at k-rows
// (reg&3)+8*(reg>>2)+4h; the PV B-fragment wants k = 8h+j. Only a half-wave
// (lane^32) exchange is needed -> 16 shfl_xor + selects per K-tile replace
// the entire P LDS round-trip (was 8 writes + 4 reads + 2-hop latency).
// K/V fragments read ONCE per wave (shared by both stacked tiles).
// ls (row sums) via mfma(ones, P). LDS = Kb+Vb dbuf = 32KB -> 4 blocks/CU.
__global__ __launch_bounds__(256, 4) void k_attn(
    const unsigned short* __restrict__ qkv,
    const unsigned short* __restrict__ vt,
    unsigned short* __restrict__ y, int T)
{
    __shared__ __align__(16) unsigned short Kb[2][64][64];
    __shared__ __align__(16) unsigned short Vb[2][64][64];
    const int nQT = T >> 6;

    // XCD-aware bijective remap (1024 = 8 * 128, exact)
    int n = blockIdx.x + gridDim.x * blockIdx.y;          // 0..1023
    n = (n & 7) * ((gridDim.x * gridDim.y) >> 3) + (n >> 3);
    const int qa = n & 15;                // 0..15
    const int qb = nQT - 1 - qa;          // 31..16
    const int bh = n >> 4;
    const int b = bh >> 4, hd = bh & 15;  // batch, head
    const int tid = threadIdx.x, w = tid >> 6, lane = tid & 63;
    const int q31 = lane & 31, h = lane >> 5, h4 = h * 4;
    const bool isA = q31 >= 16;
    const int qloc = w * 16 + (q31 & 15);              // tile-local q (0..63)
    const int q_global = (isA ? qa : qb) * 64 + qloc;  // global q row

    const float SC = 0.125f * 1.44269504f;  // 1/sqrt(64) * log2(e)

    // Q fragments: lane holds its q-row's d-halves: qf[s] = Q[q][s*16+8h .. +7]
    const unsigned short* qp = qkv + (long)(b * T + q_global) * 3072 + hd * 64 + h * 8;
    short8 qf[4];
#pragma unroll
    for (int s = 0; s < 4; ++s) {
        qf[s] = *reinterpret_cast<const short8*>(qp + s * 16);
#pragma unroll
        for (int j = 0; j < 8; ++j)
            qf[s][j] = (short)f2bf(bf2f((unsigned short)qf[s][j]) * SC);
    }

    short8 onesf;
#pragma unroll
    for (int j = 0; j < 8; ++j) onesf[j] = (short)0x3F80;

    // staging: per-lane pre-swizzled global source (rule #21 both-sides)
    const int lrow  = lane >> 3;               // row within 8-row chunk
    const int lslot = (lane & 7) ^ lrow;       // swizzled 16B source slot
    const unsigned short* kg = qkv + (long)b * T * 3072 + 1024 + hd * 64 + lslot * 8;
    const unsigned short* vg = vt + (long)bh * 64 * T + lslot * 8;

    auto stage = [&](int buf, int kt) {
#pragma unroll
        for (int i = 0; i < 2; ++i) {
            const int rb = (w * 2 + i) * 8;    // 8-row chunk base
            gl_lds16(kg + (long)(kt * 64 + rb + lrow) * 3072, &Kb[buf][rb][0]);
            gl_lds16(vg + (long)(rb + lrow) * T + kt * 64,    &Vb[buf][rb][0]);
        }
    };

    f32x16 oT[2] = {};   // O^T accumulators, d-blocks 0..1
    f32x16 ls = {};      // row sums (every m-row identical)
    int cur = 0;

    stage(0, 0);
    __syncthreads();                     // builtin vmcnt(0) drain + barrier
    for (int kt = 0; kt <= qb; ++kt) {
        if (kt < qb) stage(cur ^ 1, kt + 1);   // async DMA flies under compute

        // causal limit for this lane (tile-local k), -1 = all masked
        int qlim;
        if (!isA) qlim = (kt == qb) ? qloc : 63;
        else      qlim = (kt < qa) ? 63 : ((kt == qa) ? qloc : -1);

#pragma unroll
        for (int c2 = 0; c2 < 2; ++c2) {       // k-row blocks 0-31 / 32-63
            // S^T = K . Q^T  (A = K rows c2*32+q31, B = Q^T from regs)
            f32x16 s = {};
            __builtin_amdgcn_s_setprio(1);
#pragma unroll
            for (int s4 = 0; s4 < 4; ++s4) {
                const int r = c2 * 32 + q31;
                short8 kf = *reinterpret_cast<const short8*>(
                    &Kb[cur][r][(((s4 * 2 + h) ^ (r & 7)) * 8)]);
                s = __builtin_amdgcn_mfma_f32_32x32x16_bf16(kf, qf[s4], s, 0, 0, 0);
            }
            __builtin_amdgcn_s_setprio(0);

            // P = exp2(S) with causal mask; k-row of reg r = c2*32+(r&3)+8*(r>>2)+4h
            float p[16];
#pragma unroll
            for (int r = 0; r < 16; ++r) {
                const int kl = c2 * 32 + (r & 3) + 8 * (r >> 2) + h4;
                p[r] = (kl <= qlim) ? exp2f(s[r]) : 0.f;
            }
            // pack pairs: per k-group g (4 rows): 2 words
            unsigned int A0 = pkbf(p[0], p[1]),  B0 = pkbf(p[2], p[3]);
            unsigned int C0 = pkbf(p[4], p[5]),  D0 = pkbf(p[6], p[7]);
            unsigned int E0 = pkbf(p[8], p[9]),  F0 = pkbf(p[10], p[11]);
            unsigned int G0 = pkbf(p[12], p[13]), H0 = pkbf(p[14], p[15]);
            // half-wave exchange (lane ^ 32)
            unsigned int xA = __shfl_xor((int)A0, 32), xB = __shfl_xor((int)B0, 32);
            unsigned int xC = __shfl_xor((int)C0, 32), xD = __shfl_xor((int)D0, 32);
            unsigned int xE = __shfl_xor((int)E0, 32), xF = __shfl_xor((int)F0, 32);
            unsigned int xG = __shfl_xor((int)G0, 32), xH = __shfl_xor((int)H0, 32);

#pragma unroll
            for (int ss = 0; ss < 2; ++ss) {   // k-slices within this c2
                union { unsigned int u[4]; short8 v; } pf;
                if (ss == 0) {
                    pf.u[0] = h ? xC : A0;  pf.u[1] = h ? xD : B0;
                    pf.u[2] = h ? C0 : xA;  pf.u[3] = h ? D0 : xB;
                } else {
                    pf.u[0] = h ? xG : E0;  pf.u[1] = h ? xH : F0;
                    pf.u[2] = h ? G0 : xE;  pf.u[3] = h ? H0 : xF;
                }
                const int ks = c2 * 2 + ss;    // global k-slice (16 wide)
                __builtin_amdgcn_s_setprio(1);
                ls = __builtin_amdgcn_mfma_f32_32x32x16_bf16(onesf, pf.v, ls, 0, 0, 0);
#pragma unroll
                for (int db = 0; db < 2; ++db) {
                    const int r = db * 32 + q31;
                    short8 vf = *reinterpret_cast<const short8*>(
                        &Vb[cur][r][(((ks * 2 + h) ^ (r & 7)) * 8)]);
                    oT[db] = __builtin_amdgcn_mfma_f32_32x32x16_bf16(vf, pf.v, oT[db], 0, 0, 0);
                }
                __builtin_amdgcn_s_setprio(0);
            }
        }
        __syncthreads();                 // reads done + next tile landed
        cur ^= 1;
    }

    // epilogue: y[q][hd*64 + d] = O^T[d][q] / l[q]
    const float inv = 1.f / ls[0];
    unsigned short* yp = y + (long)(b * T + q_global) * 1024 + hd * 64;
#pragma unroll
    for (int db = 0; db < 2; ++db)
#pragma unroll
        for (int g = 0; g < 4; ++g) {
            const int d0 = db * 32 + 8 * g + h4;
            unsigned int u0 = (pkbf(0.f, oT[db][4 * g + 1] * inv) & 0xffff0000u) |
                              ((unsigned int)f2bf(oT[db][4 * g + 0] * inv));
            unsigned int u1 = (pkbf(0.f, oT[db][4 * g + 3] * inv) & 0xffff0000u) |
                              ((unsigned int)f2bf(oT[db][4 * g + 2] * inv));
            // use round-to-nearest for output quality
            u0 = ((unsigned int)f2bf(oT[db][4 * g + 1] * inv) << 16) |
                 (unsigned int)f2bf(oT[db][4 * g + 0] * inv);
            u1 = ((unsigned int)f2bf(oT[db][4 * g + 3] * inv) << 16) |
                 (unsigned int)f2bf(oT[db][4 * g + 2] * inv);
            *reinterpret_cast<uint2*>(yp + d0) = make_uint2(u0, u1);
        }
}

extern "C" void kernel_launch(void* const* d_in, const int* in_sizes, int n_in,
                              void* d_out, int out_size, void* d_ws, size_t ws_size,
                              hipStream_t stream) {
    const float* x      = (const float*)d_in[0];
    const float* w_qkv  = (const float*)d_in[1];
    const float* b_qkv  = (const float*)d_in[2];
    const float* w_proj = (const float*)d_in[3];
    const float* b_proj = (const float*)d_in[4];
    float* out = (float*)d_out;

    const int B = 4, T = 2048, C = 1024, H = 16;
    const long M = (long)B * T;  // 8192

    char* ws = (char*)d_ws;
    unsigned short* xb  = (unsigned short*)ws; ws += M * C * 2;            // 16 MB
    unsigned short* wqt = (unsigned short*)ws; ws += (long)3 * C * C * 2;  // 6 MB
    unsigned short* wpt = (unsigned short*)ws; ws += (long)C * C * 2;      // 2 MB
    unsigned short* qkv = (unsigned short*)ws; ws += M * 3 * C * 2;        // 50 MB
    unsigned short* vt  = (unsigned short*)ws; ws += M * C * 2;            // 16 MB
    unsigned short* y   = (unsigned short*)ws; ws += M * C * 2;            // 16 MB

    // 1. convert x to bf16
    k_f32_to_bf16<<<(int)((M * C / 8 + 255) / 256), 256, 0, stream>>>(x, xb, M * C);
    // 2. transpose+convert weights to [N][K] bf16
    {
        dim3 g(C / 64, 3 * C / 64);
        k_transpose_w<<<g, 256, 0, stream>>>(w_qkv, wqt, C, 3 * C);
    }
    {
        dim3 g(C / 64, C / 64);
        k_transpose_w<<<g, 256, 0, stream>>>(w_proj, wpt, C, C);
    }
    // 3. QKV GEMM -> qkv bf16 [M][3072]
    {
        dim3 g(M / 128, 3 * C / 128);
        k_gemm_bt<0><<<g, 256, 0, stream>>>(xb, wqt, b_qkv, qkv, (int)M, 3 * C, C);
    }
    // 4. V transpose -> vt[bh][64][T]
    {
        dim3 g(T / 64, B * H);
        k_transpose_v<<<g, 256, 0, stream>>>(qkv, vt, T);
    }
    // 5. causal flash attention (32x32 MFMA, in-register P) -> y
    {
        dim3 g(T / 128, B * H);
        k_attn<<<g, 256, 0, stream>>>(qkv, vt, y, T);
    }
    // 6. projection GEMM -> out f32
    {
        dim3 g(M / 128, C / 128);
        k_gemm_bt<1><<<g, 256, 0, stream>>>(y, wpt, b_proj, out, (int)M, C, C);
    }
}

// Round 12
// 180.035 us; speedup vs baseline: 1.3052x; 1.3052x over previous
//
#include <hip/hip_runtime.h>
#include <hip/hip_bf16.h>

typedef __attribute__((ext_vector_type(8))) short short8;
typedef __attribute__((ext_vector_type(4))) float f32x4;

static __device__ __forceinline__ unsigned short f2bf(float f) {
    unsigned int u = __builtin_bit_cast(unsigned int, f);
    u += 0x7fff + ((u >> 16) & 1);   // round-to-nearest-even
    return (unsigned short)(u >> 16);
}

static __device__ __forceinline__ float bf2f(unsigned short u) {
    return __builtin_bit_cast(float, (unsigned int)u << 16);
}

// direct HBM -> LDS DMA, 16B/lane; LDS dest is wave-uniform base (HW adds lane*16)
static __device__ __forceinline__ void gl_lds16(const unsigned short* g, unsigned short* l) {
    __builtin_amdgcn_global_load_lds(
        (const __attribute__((address_space(1))) unsigned int*)g,
        (__attribute__((address_space(3))) unsigned int*)l, 16, 0, 0);
}

// ---------------- fp32 -> bf16 elementwise convert (vectorized 8/thread) ----
__global__ __launch_bounds__(256) void k_f32_to_bf16(
    const float* __restrict__ in, unsigned short* __restrict__ out, long n)
{
    long i = ((long)blockIdx.x * 256 + threadIdx.x) * 8;
    if (i >= n) return;
    const f32x4 a = *reinterpret_cast<const f32x4*>(in + i);
    const f32x4 b = *reinterpret_cast<const f32x4*>(in + i + 4);
    union { unsigned short u[8]; uint4 v; } o;
    o.u[0] = f2bf(a[0]); o.u[1] = f2bf(a[1]); o.u[2] = f2bf(a[2]); o.u[3] = f2bf(a[3]);
    o.u[4] = f2bf(b[0]); o.u[5] = f2bf(b[1]); o.u[6] = f2bf(b[2]); o.u[7] = f2bf(b[3]);
    *reinterpret_cast<uint4*>(out + i) = o.v;
}

// ---------------- w [K][N] f32 -> wt [N][K] bf16 (tiled transpose) ----------
__global__ __launch_bounds__(256) void k_transpose_w(
    const float* __restrict__ w, unsigned short* __restrict__ wt, int K, int N)
{
    __shared__ unsigned short tile[64][72];
    const int k0 = blockIdx.x * 64, n0 = blockIdx.y * 64;
    const int tid = threadIdx.x;
#pragma unroll
    for (int it = 0; it < 4; ++it) {
        int idx = it * 256 + tid;          // 1024 float4 chunks
        int kl = idx >> 4;
        int nl = (idx & 15) * 4;
        f32x4 v = *reinterpret_cast<const f32x4*>(w + (long)(k0 + kl) * N + n0 + nl);
        tile[kl][nl + 0] = f2bf(v[0]);
        tile[kl][nl + 1] = f2bf(v[1]);
        tile[kl][nl + 2] = f2bf(v[2]);
        tile[kl][nl + 3] = f2bf(v[3]);
    }
    __syncthreads();
#pragma unroll
    for (int it = 0; it < 2; ++it) {
        int idx = it * 256 + tid;          // 512 chunks of 8
        int nl = idx >> 3;
        int c  = (idx & 7) * 8;
        union { unsigned short u[8]; uint4 v; } o;
#pragma unroll
        for (int j = 0; j < 8; ++j) o.u[j] = tile[c + j][nl];
        *reinterpret_cast<uint4*>(wt + (long)(n0 + nl) * K + k0 + c) = o.v;
    }
}

// ---------------- GEMM: C[M][N] = A[M][K] * Bt[N][K]^T + bias --------------
// A, Bt bf16 K-major; out bf16 (OUTF32=0) or f32 (OUTF32=1).
// v2: 2-phase double-buffered gl_lds staging (T3-minimum recipe) — the exact
// structure that took k_attn 138->105us in R6->R7. stage(next) issues before
// compute; ONE barrier per K-step (its vmcnt(0) drain lands after the loads
// flew under 32 MFMAs). Both-sides XOR swizzle (R8-verified indexing).
// R8's failure was single-buffered (latency exposed) + XCD remap; both fixed.
// LDS 64KB -> 2 blocks/CU; dbuf replaces the occupancy-based latency hiding.
template <int OUTF32>
__global__ __launch_bounds__(256) void k_gemm_bt(
    const unsigned short* __restrict__ A,
    const unsigned short* __restrict__ Bt,
    const float* __restrict__ bias,
    void* __restrict__ Cv, int M, int N, int K)
{
    __shared__ __align__(16) unsigned short As[2][128][64];
    __shared__ __align__(16) unsigned short Bs[2][128][64];
    const int tid = threadIdx.x;
    const int m0 = blockIdx.x * 128;
    const int n0 = blockIdx.y * 128;
    const int w = tid >> 6, lane = tid & 63;
    const int wr = (w >> 1) * 64, wc = (w & 1) * 64;
    const int l4 = lane >> 4, l15 = lane & 15;
    // staging: per-lane pre-swizzled global source slot
    const int lrow  = lane >> 3;               // row within 8-row chunk
    const int lslot = (lane & 7) ^ lrow;       // swizzled 16B source slot

    auto stage = [&](int buf, int k0) {
#pragma unroll
        for (int it = 0; it < 4; ++it) {
            const int rb = (w * 4 + it) * 8;   // 8-row chunk base
            gl_lds16(A  + (long)(m0 + rb + lrow) * K + k0 + lslot * 8, &As[buf][rb][0]);
            gl_lds16(Bt + (long)(n0 + rb + lrow) * K + k0 + lslot * 8, &Bs[buf][rb][0]);
        }
    };

    f32x4 acc[4][4] = {};
    const int nk = K / 64;
    int cur = 0;
    stage(0, 0);
    __syncthreads();                           // vmcnt(0) drain + barrier
    for (int kt = 0; kt < nk; ++kt) {
        if (kt + 1 < nk) stage(cur ^ 1, (kt + 1) * 64);   // flies under MFMAs
#pragma unroll
        for (int kk = 0; kk < 2; ++kk) {
            short8 af[4], bf[4];
#pragma unroll
            for (int m = 0; m < 4; ++m) {
                const int r = wr + m * 16 + l15;
                af[m] = *reinterpret_cast<const short8*>(&As[cur][r][((kk * 4 + l4) ^ (r & 7)) * 8]);
            }
#pragma unroll
            for (int n = 0; n < 4; ++n) {
                const int r = wc + n * 16 + l15;
                bf[n] = *reinterpret_cast<const short8*>(&Bs[cur][r][((kk * 4 + l4) ^ (r & 7)) * 8]);
            }
#pragma unroll
            for (int m = 0; m < 4; ++m)
#pragma unroll
                for (int n = 0; n < 4; ++n)
                    acc[m][n] = __builtin_amdgcn_mfma_f32_16x16x32_bf16(af[m], bf[n], acc[m][n], 0, 0, 0);
        }
        __syncthreads();                       // reads done + next tile landed
        cur ^= 1;
    }
    // epilogue
#pragma unroll
    for (int n = 0; n < 4; ++n) {
        const int col = n0 + wc + n * 16 + l15;
        const float bv = bias[col];
#pragma unroll
        for (int m = 0; m < 4; ++m) {
            const int row = m0 + wr + m * 16 + l4 * 4;
#pragma unroll
            for (int i = 0; i < 4; ++i) {
                float v = acc[m][n][i] + bv;
                if (OUTF32)
                    reinterpret_cast<float*>(Cv)[(long)(row + i) * N + col] = v;
                else
                    reinterpret_cast<unsigned short*>(Cv)[(long)(row + i) * N + col] = f2bf(v);
            }
        }
    }
}

// ---------------- V transpose: qkv v-part -> vt[bh][d=64][T] ---------------
__global__ __launch_bounds__(256) void k_transpose_v(
    const unsigned short* __restrict__ qkv, unsigned short* __restrict__ vt, int T)
{
    __shared__ unsigned short tile[64][72];
    const int t0 = blockIdx.x * 64, bh = blockIdx.y;
    const int b = bh >> 4, h = bh & 15;
    const int tid = threadIdx.x;
#pragma unroll
    for (int it = 0; it < 2; ++it) {
        int idx = it * 256 + tid;
        int r = idx >> 3, c = (idx & 7) * 8;
        *reinterpret_cast<uint4*>(&tile[r][c]) =
            *reinterpret_cast<const uint4*>(qkv + (long)(b * T + t0 + r) * 3072 + 2048 + h * 64 + c);
    }
    __syncthreads();
#pragma unroll
    for (int it = 0; it < 2; ++it) {
        int idx = it * 256 + tid;
        int d = idx >> 3, c = (idx & 7) * 8;
        union { unsigned short u[8]; uint4 v; } o;
#pragma unroll
        for (int j = 0; j < 8; ++j) o.u[j] = tile[c + j][d];
        *reinterpret_cast<uint4*>(vt + ((long)bh * 64 + d) * T + t0 + c) = o.v;
    }
}

// ---------------- causal flash attention v6 (R10, 82us — reverted to) ------
// Paired q-tiles sequential, gl_lds dbuf + both-sides swizzle, XCD remap,
// fixed-max softmax, MFMA row-sums, setprio, swapped QK^T + packed P-writes.
// (R11's 32x32 in-register-P variant regressed 82->136us: shfl_xor IS an
// LDS-pipe op — 32 bpermute+selects/K-tile cost more than the P round-trip,
// and the 32-row read pattern 4-way bank-conflicts. Reverted.)
__global__ __launch_bounds__(256, 4) void k_attn(
    const unsigned short* __restrict__ qkv,
    const unsigned short* __restrict__ vt,
    unsigned short* __restrict__ y, int T)
{
    __shared__ __align__(16) unsigned short Kb[2][64][64];
    __shared__ __align__(16) unsigned short Vb[2][64][64];
    __shared__ __align__(16) unsigned short Ps[4][16][64];   // [wave][q][k]
    const int nQT = T >> 6;

    // XCD-aware bijective remap (1024 = 8 * 128, exact)
    int n = blockIdx.x + gridDim.x * blockIdx.y;          // 0..1023
    n = (n & 7) * ((gridDim.x * gridDim.y) >> 3) + (n >> 3);
    const int qa = n & 15;                // 0..15
    const int qb = nQT - 1 - qa;          // 31..16
    const int bh = n >> 4;
    const int b = bh >> 4, h = bh & 15;
    const int tid = threadIdx.x, w = tid >> 6, lane = tid & 63;
    const int l4 = lane >> 4, l15 = lane & 15;

    const float SC = 0.125f * 1.44269504f;  // 1/sqrt(64) * log2(e)

    // Q fragments for both tiles, pre-scaled by SC
    const unsigned short* qpA = qkv + (long)(b * T + qa * 64 + w * 16 + l15) * 3072 + h * 64;
    const unsigned short* qpB = qkv + (long)(b * T + qb * 64 + w * 16 + l15) * 3072 + h * 64;
    short8 qfA[2], qfB[2];
    qfA[0] = *reinterpret_cast<const short8*>(qpA + l4 * 8);
    qfA[1] = *reinterpret_cast<const short8*>(qpA + 32 + l4 * 8);
    qfB[0] = *reinterpret_cast<const short8*>(qpB + l4 * 8);
    qfB[1] = *reinterpret_cast<const short8*>(qpB + 32 + l4 * 8);
#pragma unroll
    for (int kk = 0; kk < 2; ++kk)
#pragma unroll
        for (int j = 0; j < 8; ++j) {
            qfA[kk][j] = (short)f2bf(bf2f((unsigned short)qfA[kk][j]) * SC);
            qfB[kk][j] = (short)f2bf(bf2f((unsigned short)qfB[kk][j]) * SC);
        }

    // B-fragment of bf16 ones (for MFMA row-sums)
    short8 onesf;
#pragma unroll
    for (int j = 0; j < 8; ++j) onesf[j] = (short)0x3F80;

    // staging: per-lane pre-swizzled global source (rule #21 both-sides)
    const int lrow  = lane >> 3;               // row within 8-row chunk
    const int lslot = (lane & 7) ^ lrow;       // swizzled 16B source slot
    const unsigned short* kg = qkv + (long)b * T * 3072 + 1024 + h * 64 + lslot * 8;
    const unsigned short* vg = vt + (long)bh * 64 * T + lslot * 8;

    auto stage = [&](int buf, int kt) {
#pragma unroll
        for (int i = 0; i < 2; ++i) {
            const int rb = (w * 2 + i) * 8;    // 8-row chunk base
            gl_lds16(kg + (long)(kt * 64 + rb + lrow) * 3072, &Kb[buf][rb][0]);
            gl_lds16(vg + (long)(rb + lrow) * T + kt * 64,    &Vb[buf][rb][0]);
        }
    };

    f32x4 oA[4] = {}, oB[4] = {};
    f32x4 lsA = {}, lsB = {};          // MFMA-accumulated row sums
    const int qcol = w * 16 + l15;     // this lane's q-row (tile-local)
    const int pswz = (l15 & 7) << 3;   // Ps column XOR swizzle
    int cur = 0;

    // per-tile: S^T = K Q^T -> exp2/mask -> packed P-write -> O += P V, l += P 1
    auto do_tile = [&](const short8 (&qf)[2], f32x4 (&o)[4], f32x4 &ls,
                       bool diag) {
        f32x4 s[4] = {};
        __builtin_amdgcn_s_setprio(1);
#pragma unroll
        for (int kk = 0; kk < 2; ++kk)
#pragma unroll
            for (int c = 0; c < 4; ++c) {
                const int r = c * 16 + l15;
                short8 kf = *reinterpret_cast<const short8*>(
                    &Kb[cur][r][(((kk * 4 + l4) ^ (r & 7)) * 8)]);
                s[c] = __builtin_amdgcn_mfma_f32_16x16x32_bf16(kf, qf[kk], s[c], 0, 0, 0);
            }
        __builtin_amdgcn_s_setprio(0);
        // s[c][i] = S[k_local = c*16+l4*4+i][q_local = l15 (of this wave)]
#pragma unroll
        for (int c = 0; c < 4; ++c) {
            float p0 = exp2f(s[c][0]), p1 = exp2f(s[c][1]);
            float p2 = exp2f(s[c][2]), p3 = exp2f(s[c][3]);
            if (diag) {
                const int kl = c * 16 + l4 * 4;
                if (kl + 0 > qcol) p0 = 0.f;
                if (kl + 1 > qcol) p1 = 0.f;
                if (kl + 2 > qcol) p2 = 0.f;
                if (kl + 3 > qcol) p3 = 0.f;
            }
            unsigned int u01 = (__builtin_bit_cast(unsigned int, p1) & 0xffff0000u) |
                               (__builtin_bit_cast(unsigned int, p0) >> 16);
            unsigned int u23 = (__builtin_bit_cast(unsigned int, p3) & 0xffff0000u) |
                               (__builtin_bit_cast(unsigned int, p2) >> 16);
            const int colb = (c * 16 + l4 * 4) ^ pswz;
            *reinterpret_cast<uint2*>(&Ps[w][l15][colb]) = make_uint2(u01, u23);
        }
        // Ps is wave-private: in-wave ds ordering makes this safe w/o barrier
        __builtin_amdgcn_s_setprio(1);
#pragma unroll
        for (int kk = 0; kk < 2; ++kk) {
            short8 pf = *reinterpret_cast<const short8*>(
                &Ps[w][l15][(kk * 32 + l4 * 8) ^ pswz]);
            ls = __builtin_amdgcn_mfma_f32_16x16x32_bf16(pf, onesf, ls, 0, 0, 0);
#pragma unroll
            for (int nn = 0; nn < 4; ++nn) {
                const int r = nn * 16 + l15;
                short8 vf = *reinterpret_cast<const short8*>(
                    &Vb[cur][r][(((kk * 4 + l4) ^ (r & 7)) * 8)]);
                o[nn] = __builtin_amdgcn_mfma_f32_16x16x32_bf16(pf, vf, o[nn], 0, 0, 0);
            }
        }
        __builtin_amdgcn_s_setprio(0);
    };

    stage(0, 0);
    __syncthreads();                     // builtin vmcnt(0) drain + barrier
    for (int kt = 0; kt <= qb; ++kt) {
        if (kt < qb) stage(cur ^ 1, kt + 1);   // async DMA flies under compute
        do_tile(qfB, oB, lsB, kt == qb);
        if (kt <= qa) do_tile(qfA, oA, lsA, kt == qa);
        __syncthreads();                 // reads done + next tile landed
        cur ^= 1;
    }

    // epilogue: y = O / l (l already per-lane in matching layout, no reduce)
#pragma unroll
    for (int i = 0; i < 4; ++i) {
        float invA = 1.f / lsA[i];
        float invB = 1.f / lsB[i];
        int qArow = qa * 64 + w * 16 + l4 * 4 + i;
        int qBrow = qb * 64 + w * 16 + l4 * 4 + i;
        unsigned short* ypA = y + (long)(b * T + qArow) * 1024 + h * 64;
        unsigned short* ypB = y + (long)(b * T + qBrow) * 1024 + h * 64;
#pragma unroll
        for (int nn = 0; nn < 4; ++nn) {
            ypA[nn * 16 + l15] = f2bf(oA[nn][i] * invA);
            ypB[nn * 16 + l15] = f2bf(oB[nn][i] * invB);
        }
    }
}

extern "C" void kernel_launch(void* const* d_in, const int* in_sizes, int n_in,
                              void* d_out, int out_size, void* d_ws, size_t ws_size,
                              hipStream_t stream) {
    const float* x      = (const float*)d_in[0];
    const float* w_qkv  = (const float*)d_in[1];
    const float* b_qkv  = (const float*)d_in[2];
    const float* w_proj = (const float*)d_in[3];
    const float* b_proj = (const float*)d_in[4];
    float* out = (float*)d_out;

    const int B = 4, T = 2048, C = 1024, H = 16;
    const long M = (long)B * T;  // 8192

    char* ws = (char*)d_ws;
    unsigned short* xb  = (unsigned short*)ws; ws += M * C * 2;            // 16 MB
    unsigned short* wqt = (unsigned short*)ws; ws += (long)3 * C * C * 2;  // 6 MB
    unsigned short* wpt = (unsigned short*)ws; ws += (long)C * C * 2;      // 2 MB
    unsigned short* qkv = (unsigned short*)ws; ws += M * 3 * C * 2;        // 50 MB
    unsigned short* vt  = (unsigned short*)ws; ws += M * C * 2;            // 16 MB
    unsigned short* y   = (unsigned short*)ws; ws += M * C * 2;            // 16 MB

    // 1. convert x to bf16
    k_f32_to_bf16<<<(int)((M * C / 8 + 255) / 256), 256, 0, stream>>>(x, xb, M * C);
    // 2. transpose+convert weights to [N][K] bf16
    {
        dim3 g(C / 64, 3 * C / 64);
        k_transpose_w<<<g, 256, 0, stream>>>(w_qkv, wqt, C, 3 * C);
    }
    {
        dim3 g(C / 64, C / 64);
        k_transpose_w<<<g, 256, 0, stream>>>(w_proj, wpt, C, C);
    }
    // 3. QKV GEMM (2-phase dbuf) -> qkv bf16 [M][3072]
    {
        dim3 g(M / 128, 3 * C / 128);
        k_gemm_bt<0><<<g, 256, 0, stream>>>(xb, wqt, b_qkv, qkv, (int)M, 3 * C, C);
    }
    // 4. V transpose -> vt[bh][64][T]
    {
        dim3 g(T / 64, B * H);
        k_transpose_v<<<g, 256, 0, stream>>>(qkv, vt, T);
    }
    // 5. causal flash attention (R10 v6) -> y bf16 [M][1024]
    {
        dim3 g(T / 128, B * H);
        k_attn<<<g, 256, 0, stream>>>(qkv, vt, y, T);
    }
    // 6. projection GEMM (2-phase dbuf) -> out f32
    {
        dim3 g(M / 128, C / 128);
        k_gemm_bt<1><<<g, 256, 0, stream>>>(y, wpt, b_proj, out, (int)M, C, C);
    }
}

// Round 13
// 179.311 us; speedup vs baseline: 1.3105x; 1.0040x over previous
//
#include <hip/hip_runtime.h>
#include <hip/hip_bf16.h>

typedef __attribute__((ext_vector_type(8))) short short8;
typedef __attribute__((ext_vector_type(4))) float f32x4;

static __device__ __forceinline__ unsigned short f2bf(float f) {
    unsigned int u = __builtin_bit_cast(unsigned int, f);
    u += 0x7fff + ((u >> 16) & 1);   // round-to-nearest-even
    return (unsigned short)(u >> 16);
}

static __device__ __forceinline__ float bf2f(unsigned short u) {
    return __builtin_bit_cast(float, (unsigned int)u << 16);
}

// direct HBM -> LDS DMA, 16B/lane; LDS dest is wave-uniform base (HW adds lane*16)
static __device__ __forceinline__ void gl_lds16(const unsigned short* g, unsigned short* l) {
    __builtin_amdgcn_global_load_lds(
        (const __attribute__((address_space(1))) unsigned int*)g,
        (__attribute__((address_space(3))) unsigned int*)l, 16, 0, 0);
}

// ---------------- fp32 -> bf16 elementwise convert (vectorized 8/thread) ----
__global__ __launch_bounds__(256) void k_f32_to_bf16(
    const float* __restrict__ in, unsigned short* __restrict__ out, long n)
{
    long i = ((long)blockIdx.x * 256 + threadIdx.x) * 8;
    if (i >= n) return;
    const f32x4 a = *reinterpret_cast<const f32x4*>(in + i);
    const f32x4 b = *reinterpret_cast<const f32x4*>(in + i + 4);
    union { unsigned short u[8]; uint4 v; } o;
    o.u[0] = f2bf(a[0]); o.u[1] = f2bf(a[1]); o.u[2] = f2bf(a[2]); o.u[3] = f2bf(a[3]);
    o.u[4] = f2bf(b[0]); o.u[5] = f2bf(b[1]); o.u[6] = f2bf(b[2]); o.u[7] = f2bf(b[3]);
    *reinterpret_cast<uint4*>(out + i) = o.v;
}

// ---------------- w [K][N] f32 -> wt [N][K] bf16 (tiled transpose) ----------
__global__ __launch_bounds__(256) void k_transpose_w(
    const float* __restrict__ w, unsigned short* __restrict__ wt, int K, int N)
{
    __shared__ unsigned short tile[64][72];
    const int k0 = blockIdx.x * 64, n0 = blockIdx.y * 64;
    const int tid = threadIdx.x;
#pragma unroll
    for (int it = 0; it < 4; ++it) {
        int idx = it * 256 + tid;          // 1024 float4 chunks
        int kl = idx >> 4;
        int nl = (idx & 15) * 4;
        f32x4 v = *reinterpret_cast<const f32x4*>(w + (long)(k0 + kl) * N + n0 + nl);
        tile[kl][nl + 0] = f2bf(v[0]);
        tile[kl][nl + 1] = f2bf(v[1]);
        tile[kl][nl + 2] = f2bf(v[2]);
        tile[kl][nl + 3] = f2bf(v[3]);
    }
    __syncthreads();
#pragma unroll
    for (int it = 0; it < 2; ++it) {
        int idx = it * 256 + tid;          // 512 chunks of 8
        int nl = idx >> 3;
        int c  = (idx & 7) * 8;
        union { unsigned short u[8]; uint4 v; } o;
#pragma unroll
        for (int j = 0; j < 8; ++j) o.u[j] = tile[c + j][nl];
        *reinterpret_cast<uint4*>(wt + (long)(n0 + nl) * K + k0 + c) = o.v;
    }
}

// ---------------- GEMM: C[M][N] = A[M][K] * Bt[N][K]^T + bias --------------
// A, Bt bf16 K-major; out bf16 (OUTF32=0) or f32 (OUTF32=1).
// v3: 2-phase dbuf gl_lds + COUNTED vmcnt (T4). The old __syncthreads drained
// vmcnt(0) at end-of-iter, waiting for the just-issued next-tile loads
// (stall = latency - 1 compute phase). Now: lagged vmcnt(8) at iter top waits
// only for stage-kt (issued a full iteration ago) while stage-kt+1's 8 loads
// stay in flight across the barrier. Race-safety: (a) vmcnt(8)+barrier =>
// all waves' stage-kt landed before reads; (b) stage(kt+1) overwrites the
// buffer last read in iter kt-1, and every wave passed iter kt-1's
// end-barrier before any wave issues it. Control flow is all-wave-uniform.
template <int OUTF32>
__global__ __launch_bounds__(256) void k_gemm_bt(
    const unsigned short* __restrict__ A,
    const unsigned short* __restrict__ Bt,
    const float* __restrict__ bias,
    void* __restrict__ Cv, int M, int N, int K)
{
    __shared__ __align__(16) unsigned short As[2][128][64];
    __shared__ __align__(16) unsigned short Bs[2][128][64];
    const int tid = threadIdx.x;
    const int m0 = blockIdx.x * 128;
    const int n0 = blockIdx.y * 128;
    const int w = tid >> 6, lane = tid & 63;
    const int wr = (w >> 1) * 64, wc = (w & 1) * 64;
    const int l4 = lane >> 4, l15 = lane & 15;
    // staging: per-lane pre-swizzled global source slot
    const int lrow  = lane >> 3;               // row within 8-row chunk
    const int lslot = (lane & 7) ^ lrow;       // swizzled 16B source slot

    auto stage = [&](int buf, int k0) {        // 8 gl_lds per wave
#pragma unroll
        for (int it = 0; it < 4; ++it) {
            const int rb = (w * 4 + it) * 8;   // 8-row chunk base
            gl_lds16(A  + (long)(m0 + rb + lrow) * K + k0 + lslot * 8, &As[buf][rb][0]);
            gl_lds16(Bt + (long)(n0 + rb + lrow) * K + k0 + lslot * 8, &Bs[buf][rb][0]);
        }
    };

    f32x4 acc[4][4] = {};
    const int nk = K / 64;
    stage(0, 0);
    for (int kt = 0; kt < nk; ++kt) {
        const int cur = kt & 1;
        if (kt + 1 < nk) {
            stage(cur ^ 1, (kt + 1) * 64);     // 8 loads stay in flight
            asm volatile("s_waitcnt vmcnt(8)" ::: "memory");   // stage-kt landed
        } else {
            asm volatile("s_waitcnt vmcnt(0)" ::: "memory");
        }
        __builtin_amdgcn_sched_barrier(0);
        __builtin_amdgcn_s_barrier();          // all waves' stage-kt landed
        __builtin_amdgcn_sched_barrier(0);
#pragma unroll
        for (int kk = 0; kk < 2; ++kk) {
            short8 af[4], bf[4];
#pragma unroll
            for (int m = 0; m < 4; ++m) {
                const int r = wr + m * 16 + l15;
                af[m] = *reinterpret_cast<const short8*>(&As[cur][r][((kk * 4 + l4) ^ (r & 7)) * 8]);
            }
#pragma unroll
            for (int n = 0; n < 4; ++n) {
                const int r = wc + n * 16 + l15;
                bf[n] = *reinterpret_cast<const short8*>(&Bs[cur][r][((kk * 4 + l4) ^ (r & 7)) * 8]);
            }
#pragma unroll
            for (int m = 0; m < 4; ++m)
#pragma unroll
                for (int n = 0; n < 4; ++n)
                    acc[m][n] = __builtin_amdgcn_mfma_f32_16x16x32_bf16(af[m], bf[n], acc[m][n], 0, 0, 0);
        }
        __builtin_amdgcn_sched_barrier(0);
        asm volatile("s_waitcnt lgkmcnt(0)" ::: "memory");   // my LDS reads done
        __builtin_amdgcn_s_barrier();          // everyone's reads done -> buffer reusable
        __builtin_amdgcn_sched_barrier(0);
    }
    // epilogue
#pragma unroll
    for (int n = 0; n < 4; ++n) {
        const int col = n0 + wc + n * 16 + l15;
        const float bv = bias[col];
#pragma unroll
        for (int m = 0; m < 4; ++m) {
            const int row = m0 + wr + m * 16 + l4 * 4;
#pragma unroll
            for (int i = 0; i < 4; ++i) {
                float v = acc[m][n][i] + bv;
                if (OUTF32)
                    reinterpret_cast<float*>(Cv)[(long)(row + i) * N + col] = v;
                else
                    reinterpret_cast<unsigned short*>(Cv)[(long)(row + i) * N + col] = f2bf(v);
            }
        }
    }
}

// ---------------- V transpose: qkv v-part -> vt[bh][d=64][T] ---------------
__global__ __launch_bounds__(256) void k_transpose_v(
    const unsigned short* __restrict__ qkv, unsigned short* __restrict__ vt, int T)
{
    __shared__ unsigned short tile[64][72];
    const int t0 = blockIdx.x * 64, bh = blockIdx.y;
    const int b = bh >> 4, h = bh & 15;
    const int tid = threadIdx.x;
#pragma unroll
    for (int it = 0; it < 2; ++it) {
        int idx = it * 256 + tid;
        int r = idx >> 3, c = (idx & 7) * 8;
        *reinterpret_cast<uint4*>(&tile[r][c]) =
            *reinterpret_cast<const uint4*>(qkv + (long)(b * T + t0 + r) * 3072 + 2048 + h * 64 + c);
    }
    __syncthreads();
#pragma unroll
    for (int it = 0; it < 2; ++it) {
        int idx = it * 256 + tid;
        int d = idx >> 3, c = (idx & 7) * 8;
        union { unsigned short u[8]; uint4 v; } o;
#pragma unroll
        for (int j = 0; j < 8; ++j) o.u[j] = tile[c + j][d];
        *reinterpret_cast<uint4*>(vt + ((long)bh * 64 + d) * T + t0 + c) = o.v;
    }
}

// ---------------- causal flash attention v6 (R10/R12 known-good, 82us) -----
// Paired q-tiles sequential, gl_lds dbuf + both-sides swizzle, XCD remap,
// fixed-max softmax, MFMA row-sums, setprio, swapped QK^T + packed P-writes.
__global__ __launch_bounds__(256, 4) void k_attn(
    const unsigned short* __restrict__ qkv,
    const unsigned short* __restrict__ vt,
    unsigned short* __restrict__ y, int T)
{
    __shared__ __align__(16) unsigned short Kb[2][64][64];
    __shared__ __align__(16) unsigned short Vb[2][64][64];
    __shared__ __align__(16) unsigned short Ps[4][16][64];   // [wave][q][k]
    const int nQT = T >> 6;

    // XCD-aware bijective remap (1024 = 8 * 128, exact)
    int n = blockIdx.x + gridDim.x * blockIdx.y;          // 0..1023
    n = (n & 7) * ((gridDim.x * gridDim.y) >> 3) + (n >> 3);
    const int qa = n & 15;                // 0..15
    const int qb = nQT - 1 - qa;          // 31..16
    const int bh = n >> 4;
    const int b = bh >> 4, h = bh & 15;
    const int tid = threadIdx.x, w = tid >> 6, lane = tid & 63;
    const int l4 = lane >> 4, l15 = lane & 15;

    const float SC = 0.125f * 1.44269504f;  // 1/sqrt(64) * log2(e)

    // Q fragments for both tiles, pre-scaled by SC
    const unsigned short* qpA = qkv + (long)(b * T + qa * 64 + w * 16 + l15) * 3072 + h * 64;
    const unsigned short* qpB = qkv + (long)(b * T + qb * 64 + w * 16 + l15) * 3072 + h * 64;
    short8 qfA[2], qfB[2];
    qfA[0] = *reinterpret_cast<const short8*>(qpA + l4 * 8);
    qfA[1] = *reinterpret_cast<const short8*>(qpA + 32 + l4 * 8);
    qfB[0] = *reinterpret_cast<const short8*>(qpB + l4 * 8);
    qfB[1] = *reinterpret_cast<const short8*>(qpB + 32 + l4 * 8);
#pragma unroll
    for (int kk = 0; kk < 2; ++kk)
#pragma unroll
        for (int j = 0; j < 8; ++j) {
            qfA[kk][j] = (short)f2bf(bf2f((unsigned short)qfA[kk][j]) * SC);
            qfB[kk][j] = (short)f2bf(bf2f((unsigned short)qfB[kk][j]) * SC);
        }

    // B-fragment of bf16 ones (for MFMA row-sums)
    short8 onesf;
#pragma unroll
    for (int j = 0; j < 8; ++j) onesf[j] = (short)0x3F80;

    // staging: per-lane pre-swizzled global source (rule #21 both-sides)
    const int lrow  = lane >> 3;               // row within 8-row chunk
    const int lslot = (lane & 7) ^ lrow;       // swizzled 16B source slot
    const unsigned short* kg = qkv + (long)b * T * 3072 + 1024 + h * 64 + lslot * 8;
    const unsigned short* vg = vt + (long)bh * 64 * T + lslot * 8;

    auto stage = [&](int buf, int kt) {
#pragma unroll
        for (int i = 0; i < 2; ++i) {
            const int rb = (w * 2 + i) * 8;    // 8-row chunk base
            gl_lds16(kg + (long)(kt * 64 + rb + lrow) * 3072, &Kb[buf][rb][0]);
            gl_lds16(vg + (long)(rb + lrow) * T + kt * 64,    &Vb[buf][rb][0]);
        }
    };

    f32x4 oA[4] = {}, oB[4] = {};
    f32x4 lsA = {}, lsB = {};          // MFMA-accumulated row sums
    const int qcol = w * 16 + l15;     // this lane's q-row (tile-local)
    const int pswz = (l15 & 7) << 3;   // Ps column XOR swizzle
    int cur = 0;

    // per-tile: S^T = K Q^T -> exp2/mask -> packed P-write -> O += P V, l += P 1
    auto do_tile = [&](const short8 (&qf)[2], f32x4 (&o)[4], f32x4 &ls,
                       bool diag) {
        f32x4 s[4] = {};
        __builtin_amdgcn_s_setprio(1);
#pragma unroll
        for (int kk = 0; kk < 2; ++kk)
#pragma unroll
            for (int c = 0; c < 4; ++c) {
                const int r = c * 16 + l15;
                short8 kf = *reinterpret_cast<const short8*>(
                    &Kb[cur][r][(((kk * 4 + l4) ^ (r & 7)) * 8)]);
                s[c] = __builtin_amdgcn_mfma_f32_16x16x32_bf16(kf, qf[kk], s[c], 0, 0, 0);
            }
        __builtin_amdgcn_s_setprio(0);
        // s[c][i] = S[k_local = c*16+l4*4+i][q_local = l15 (of this wave)]
#pragma unroll
        for (int c = 0; c < 4; ++c) {
            float p0 = exp2f(s[c][0]), p1 = exp2f(s[c][1]);
            float p2 = exp2f(s[c][2]), p3 = exp2f(s[c][3]);
            if (diag) {
                const int kl = c * 16 + l4 * 4;
                if (kl + 0 > qcol) p0 = 0.f;
                if (kl + 1 > qcol) p1 = 0.f;
                if (kl + 2 > qcol) p2 = 0.f;
                if (kl + 3 > qcol) p3 = 0.f;
            }
            unsigned int u01 = (__builtin_bit_cast(unsigned int, p1) & 0xffff0000u) |
                               (__builtin_bit_cast(unsigned int, p0) >> 16);
            unsigned int u23 = (__builtin_bit_cast(unsigned int, p3) & 0xffff0000u) |
                               (__builtin_bit_cast(unsigned int, p2) >> 16);
            const int colb = (c * 16 + l4 * 4) ^ pswz;
            *reinterpret_cast<uint2*>(&Ps[w][l15][colb]) = make_uint2(u01, u23);
        }
        // Ps is wave-private: in-wave ds ordering makes this safe w/o barrier
        __builtin_amdgcn_s_setprio(1);
#pragma unroll
        for (int kk = 0; kk < 2; ++kk) {
            short8 pf = *reinterpret_cast<const short8*>(
                &Ps[w][l15][(kk * 32 + l4 * 8) ^ pswz]);
            ls = __builtin_amdgcn_mfma_f32_16x16x32_bf16(pf, onesf, ls, 0, 0, 0);
#pragma unroll
            for (int nn = 0; nn < 4; ++nn) {
                const int r = nn * 16 + l15;
                short8 vf = *reinterpret_cast<const short8*>(
                    &Vb[cur][r][(((kk * 4 + l4) ^ (r & 7)) * 8)]);
                o[nn] = __builtin_amdgcn_mfma_f32_16x16x32_bf16(pf, vf, o[nn], 0, 0, 0);
            }
        }
        __builtin_amdgcn_s_setprio(0);
    };

    stage(0, 0);
    __syncthreads();                     // builtin vmcnt(0) drain + barrier
    for (int kt = 0; kt <= qb; ++kt) {
        if (kt < qb) stage(cur ^ 1, kt + 1);   // async DMA flies under compute
        do_tile(qfB, oB, lsB, kt == qb);
        if (kt <= qa) do_tile(qfA, oA, lsA, kt == qa);
        __syncthreads();                 // reads done + next tile landed
        cur ^= 1;
    }

    // epilogue: y = O / l (l already per-lane in matching layout, no reduce)
#pragma unroll
    for (int i = 0; i < 4; ++i) {
        float invA = 1.f / lsA[i];
        float invB = 1.f / lsB[i];
        int qArow = qa * 64 + w * 16 + l4 * 4 + i;
        int qBrow = qb * 64 + w * 16 + l4 * 4 + i;
        unsigned short* ypA = y + (long)(b * T + qArow) * 1024 + h * 64;
        unsigned short* ypB = y + (long)(b * T + qBrow) * 1024 + h * 64;
#pragma unroll
        for (int nn = 0; nn < 4; ++nn) {
            ypA[nn * 16 + l15] = f2bf(oA[nn][i] * invA);
            ypB[nn * 16 + l15] = f2bf(oB[nn][i] * invB);
        }
    }
}

extern "C" void kernel_launch(void* const* d_in, const int* in_sizes, int n_in,
                              void* d_out, int out_size, void* d_ws, size_t ws_size,
                              hipStream_t stream) {
    const float* x      = (const float*)d_in[0];
    const float* w_qkv  = (const float*)d_in[1];
    const float* b_qkv  = (const float*)d_in[2];
    const float* w_proj = (const float*)d_in[3];
    const float* b_proj = (const float*)d_in[4];
    float* out = (float*)d_out;

    const int B = 4, T = 2048, C = 1024, H = 16;
    const long M = (long)B * T;  // 8192

    char* ws = (char*)d_ws;
    unsigned short* xb  = (unsigned short*)ws; ws += M * C * 2;            // 16 MB
    unsigned short* wqt = (unsigned short*)ws; ws += (long)3 * C * C * 2;  // 6 MB
    unsigned short* wpt = (unsigned short*)ws; ws += (long)C * C * 2;      // 2 MB
    unsigned short* qkv = (unsigned short*)ws; ws += M * 3 * C * 2;        // 50 MB
    unsigned short* vt  = (unsigned short*)ws; ws += M * C * 2;            // 16 MB
    unsigned short* y   = (unsigned short*)ws; ws += M * C * 2;            // 16 MB

    // 1. convert x to bf16
    k_f32_to_bf16<<<(int)((M * C / 8 + 255) / 256), 256, 0, stream>>>(x, xb, M * C);
    // 2. transpose+convert weights to [N][K] bf16
    {
        dim3 g(C / 64, 3 * C / 64);
        k_transpose_w<<<g, 256, 0, stream>>>(w_qkv, wqt, C, 3 * C);
    }
    {
        dim3 g(C / 64, C / 64);
        k_transpose_w<<<g, 256, 0, stream>>>(w_proj, wpt, C, C);
    }
    // 3. QKV GEMM (2-phase dbuf, counted vmcnt) -> qkv bf16 [M][3072]
    {
        dim3 g(M / 128, 3 * C / 128);
        k_gemm_bt<0><<<g, 256, 0, stream>>>(xb, wqt, b_qkv, qkv, (int)M, 3 * C, C);
    }
    // 4. V transpose -> vt[bh][64][T]
    {
        dim3 g(T / 64, B * H);
        k_transpose_v<<<g, 256, 0, stream>>>(qkv, vt, T);
    }
    // 5. causal flash attention (R12 known-good) -> y bf16 [M][1024]
    {
        dim3 g(T / 128, B * H);
        k_attn<<<g, 256, 0, stream>>>(qkv, vt, y, T);
    }
    // 6. projection GEMM (2-phase dbuf, counted vmcnt) -> out f32
    {
        dim3 g(M / 128, C / 128);
        k_gemm_bt<1><<<g, 256, 0, stream>>>(y, wpt, b_proj, out, (int)M, C, C);
    }
}